// Round 21
// baseline (97.617 us; speedup 1.0000x reference)
//
#include <hip/hip_runtime.h>
#include <hip/hip_bf16.h>
#include <math.h>

typedef __attribute__((ext_vector_type(4))) float f32x4;
typedef __attribute__((ext_vector_type(8))) float f32x8;
typedef __bf16 bf16x8 __attribute__((ext_vector_type(8)));
typedef unsigned short u16;
typedef u16 u16x8 __attribute__((ext_vector_type(8)));
typedef void __attribute__((address_space(1))) * as1p;
typedef void __attribute__((address_space(3))) * as3p;

__device__ __forceinline__ unsigned short f2bf(float f) {
    union { float f; unsigned int u; } v; v.f = f;
    unsigned int u = v.u;
    u += 0x7fffu + ((u >> 16) & 1u);   // RNE
    return (unsigned short)(u >> 16);
}

__device__ __forceinline__ float bf2f(unsigned short b) {
    union { unsigned int u; float f; } v;
    v.u = ((unsigned int)b) << 16;
    return v.f;
}

__device__ __forceinline__ float fast_tanh(float v) {
    float vc = fminf(fmaxf(v, -15.f), 15.f);
    float e = __expf(2.f * vc);
    return (e - 1.f) / (e + 1.f);
}

// ---------- fused prepass: cvt x,h -> bf16 AND 3 weight transposes ----------
__global__ void prep_k(const float* __restrict__ x, const float* __restrict__ h,
                       const float* __restrict__ wz, const float* __restrict__ wrr,
                       const float* __restrict__ wh,
                       u16* __restrict__ xb, u16* __restrict__ hb,
                       u16* __restrict__ wzt, u16* __restrict__ wrt, u16* __restrict__ wht) {
    __shared__ float t[32][33];
    int bid = blockIdx.x;
    int tid = threadIdx.x;
    if (bid < 2048) {
        const int n4 = 16384 * 512 / 4;
        int i = bid * 256 + tid;
        const int stride = 2048 * 256;
        const float4* x4 = (const float4*)x;
        const float4* h4 = (const float4*)h;
        ushort4* xb4 = (ushort4*)xb;
        ushort4* hb4 = (ushort4*)hb;
        for (; i < n4; i += stride) {
            float4 v = x4[i];
            xb4[i] = make_ushort4(f2bf(v.x), f2bf(v.y), f2bf(v.z), f2bf(v.w));
            float4 w = h4[i];
            hb4[i] = make_ushort4(f2bf(w.x), f2bf(w.y), f2bf(w.z), f2bf(w.w));
        }
    } else {
        int b = bid - 2048;
        int z = b >> 9;
        int rem = b & 511;
        const float* src = (z == 0) ? wz : (z == 1) ? wrr : wh;
        u16* dst = (z == 0) ? wzt : (z == 1) ? wrt : wht;
        int n0 = (rem & 15) * 32;
        int k0 = (rem >> 4) * 32;
        int tx = tid & 31, ty = tid >> 5;
#pragma unroll
        for (int i = 0; i < 4; ++i)
            t[ty + i * 8][tx] = src[(size_t)(k0 + ty + i * 8) * 512 + n0 + tx];
        __syncthreads();
#pragma unroll
        for (int i = 0; i < 4; ++i)
            dst[(size_t)(n0 + ty + i * 8) * 1024 + k0 + tx] = f2bf(t[tx][ty + i * 8]);
    }
}

// ================= BK=64 machinery (128B rows, row&7 swizzle — conflicts=0) =================
__device__ __forceinline__ void stage_sw(const u16* g, int gstride, u16* lds, int tid) {
#pragma unroll
    for (int i = 0; i < 4; ++i) {
        int ob = i * 4096 + ((tid >> 6) << 10);
        int o = ob + ((tid & 63) << 4);
        int row = o >> 7;
        int cb = (o & 127) ^ ((row & 7) << 4);
        const u16* gp = g + (size_t)row * gstride + (cb >> 1);
        __builtin_amdgcn_global_load_lds((as1p)(void*)gp, (as3p)(void*)(lds + (ob >> 1)), 16, 0, 0);
    }
}

__device__ __forceinline__ bf16x8 ld_frag(const u16* region, int r, int kb) {
    int byte = (r << 7) + (kb ^ ((r & 7) << 4));
    return *(const bf16x8*)((const char*)region + byte);
}

__device__ __forceinline__ void compute_tile(const u16* LA, const u16* LB,
                                             int wr, int wc, int l, f32x4 (&acc)[4][4]) {
    int fr = l & 15;
    int kbb = (l >> 4) << 4;
#pragma unroll
    for (int q = 0; q < 2; ++q) {
        bf16x8 a[4], b[4];
#pragma unroll
        for (int m = 0; m < 4; ++m)
            a[m] = ld_frag(LA, wr * 64 + m * 16 + fr, q * 64 + kbb);
#pragma unroll
        for (int n = 0; n < 4; ++n)
            b[n] = ld_frag(LB, wc * 64 + n * 16 + fr, q * 64 + kbb);
#pragma unroll
        for (int m = 0; m < 4; ++m)
#pragma unroll
            for (int n = 0; n < 4; ++n)
                acc[m][n] = __builtin_amdgcn_mfma_f32_16x16x32_bf16(a[m], b[n], acc[m][n], 0, 0, 0);
    }
}

template<typename AF, typename BF>
__device__ __forceinline__ void kloop(AF ga, BF gb, u16* lds, int tid,
                                      int wr, int wc, int l, f32x4 (&acc)[4][4]) {
    stage_sw(ga(0), 512, lds, tid);
    stage_sw(gb(0), 1024, lds + 8192, tid);
    __syncthreads();
#pragma unroll
    for (int i = 0; i < 15; ++i) {
        u16* nxt = lds + ((i + 1) & 1) * 16384;
        const u16* cur = lds + (i & 1) * 16384;
        stage_sw(ga(i + 1), 512, nxt, tid);
        stage_sw(gb(i + 1), 1024, nxt + 8192, tid);
        compute_tile(cur, cur + 8192, wr, wc, l, acc);
        __syncthreads();
    }
    compute_tile(lds + 16384, lds + 16384 + 8192, wr, wc, l, acc);
}

// ---------- scatter acc into f32 [128][128] LDS tile ----------
__device__ __forceinline__ void scatter_acc(float* tf, const f32x4 (&acc)[4][4],
                                            int wr, int wc, int l) {
    int colb = wc * 64;
    int rowb = wr * 64 + ((l >> 4) << 2);
#pragma unroll
    for (int n = 0; n < 4; ++n) {
        int col = colb + n * 16 + (l & 15);
#pragma unroll
        for (int m = 0; m < 4; ++m) {
            int row0 = rowb + m * 16;
#pragma unroll
            for (int r = 0; r < 4; ++r)
                tf[(row0 + r) * 128 + col] = acc[m][n][r];
        }
    }
}

// ================= gr: [X|H] @ Wr^T -> rgh = bf16(sigmoid * h) =================
__global__ __launch_bounds__(256) void gr_k(
    const u16* __restrict__ Xb, const u16* __restrict__ Hb, const u16* __restrict__ Wt,
    const float* __restrict__ rb_, u16* __restrict__ rgh) {
    __shared__ u16 lds[2 * 16384];
    int tid = threadIdx.x;
    int l = tid & 63, w = tid >> 6;
    int wr = w >> 1, wc = w & 1;
    int swz = (blockIdx.x & 7) * 64 + (blockIdx.x >> 3);
    int mb = swz >> 2, nb = swz & 3;
    int m0 = mb * 128, n0 = nb * 128;
    f32x4 acc[4][4];
#pragma unroll
    for (int m = 0; m < 4; ++m)
#pragma unroll
        for (int n = 0; n < 4; ++n) acc[m][n] = (f32x4){0.f, 0.f, 0.f, 0.f};

    auto ga = [&](int t) -> const u16* {
        return (t < 8) ? (Xb + (size_t)m0 * 512 + t * 64)
                       : (Hb + (size_t)m0 * 512 + (t - 8) * 64);
    };
    auto gb = [&](int t) -> const u16* { return Wt + (size_t)n0 * 1024 + t * 64; };
    kloop(ga, gb, lds, tid, wr, wc, l, acc);

    __syncthreads();
    float* tf = (float*)lds;
    scatter_acc(tf, acc, wr, wc, l);
    __syncthreads();
#pragma unroll
    for (int i = 0; i < 8; ++i) {
        int chunk = i * 256 + tid;
        int row = chunk >> 4;
        int c8 = (chunk & 15) << 3;
        const float* src = &tf[row * 128 + c8];
        int gcol = n0 + c8;
        size_t gbase = (size_t)(m0 + row) * 512 + gcol;
        u16x8 h8 = *(const u16x8*)&Hb[gbase];
        u16x8 o;
#pragma unroll
        for (int j = 0; j < 8; ++j) {
            float v = src[j] + rb_[gcol + j];
            float s = 1.f / (1.f + __expf(-v));
            o[j] = f2bf(s * bf2f(h8[j]));
        }
        *(u16x8*)&rgh[gbase] = o;
    }
}

// ================= BK=32 machinery =================
__device__ __forceinline__ void stage32(const u16* g, int gstride, u16* region, int tid) {
#pragma unroll
    for (int i = 0; i < 2; ++i) {
        int ob = i * 4096 + ((tid >> 6) << 10);
        int o = ob + ((tid & 63) << 4);
        int row = o >> 6;
        int cb = (o & 63) ^ ((row & 3) << 4);
        const u16* gp = g + (size_t)row * gstride + (cb >> 1);
        __builtin_amdgcn_global_load_lds((as1p)(void*)gp, (as3p)(void*)(region + (ob >> 1)), 16, 0, 0);
    }
}

__device__ __forceinline__ bf16x8 ld32(const u16* region, int r, int kb) {
    int byte = (r << 6) + (kb ^ ((r & 3) << 4));
    return *(const bf16x8*)((const char*)region + byte);
}

// ================= ghz: fused z-gate + hidden GEMM -> out fp32 =================
__global__ __launch_bounds__(256, 2) void ghz_k(
    const u16* __restrict__ Xb, const u16* __restrict__ Hb, const u16* __restrict__ rgh,
    const u16* __restrict__ Wht, const u16* __restrict__ Wzt,
    const float* __restrict__ ub, const float* __restrict__ hb,
    float* __restrict__ out) {
    __shared__ u16 lds[2 * 16384];
    int tid = threadIdx.x;
    int l = tid & 63, w = tid >> 6;
    int wr = w >> 1, wc = w & 1;
    int swz = (blockIdx.x & 7) * 64 + (blockIdx.x >> 3);
    int mb = swz >> 2, nb = swz & 3;
    int m0 = mb * 128, n0 = nb * 128;

    f32x4 acc_h[4][4], acc_z[4][4];
#pragma unroll
    for (int m = 0; m < 4; ++m)
#pragma unroll
        for (int n = 0; n < 4; ++n) {
            acc_h[m][n] = (f32x4){0.f, 0.f, 0.f, 0.f};
            acc_z[m][n] = (f32x4){0.f, 0.f, 0.f, 0.f};
        }

    auto ah = [&](int t) -> const u16* {
        return (t < 16) ? (Xb + (size_t)m0 * 512 + t * 32)
                        : (rgh + (size_t)m0 * 512 + (t - 16) * 32);
    };
    auto az = [&](int t) -> const u16* {
        return Hb + (size_t)m0 * 512 + (t - 16) * 32;
    };
    auto bhp = [&](int t) -> const u16* { return Wht + (size_t)n0 * 1024 + t * 32; };
    auto bzp = [&](int t) -> const u16* { return Wzt + (size_t)n0 * 1024 + t * 32; };

    const int fr = l & 15;
    const int kbb = (l >> 4) << 4;

    stage32(ah(0), 512, lds, tid);
    stage32(bhp(0), 1024, lds + 8192, tid);
    stage32(bzp(0), 1024, lds + 12288, tid);
    __syncthreads();

#pragma unroll
    for (int i = 0; i < 32; ++i) {
        const u16* cur = lds + (i & 1) * 16384;
        if (i < 31) {
            u16* nxt = lds + ((i + 1) & 1) * 16384;
            stage32(ah(i + 1), 512, nxt, tid);
            if (i + 1 >= 16) stage32(az(i + 1), 512, nxt + 4096, tid);
            stage32(bhp(i + 1), 1024, nxt + 8192, tid);
            stage32(bzp(i + 1), 1024, nxt + 12288, tid);
        }
        const u16* Ahr = cur;
        const u16* Azr = (i < 16) ? cur : (cur + 4096);
        const u16* Bhr = cur + 8192;
        const u16* Bzr = cur + 12288;
        bf16x8 a[4], azf[4], bh4[4], bz4[4];
#pragma unroll
        for (int m = 0; m < 4; ++m) {
            a[m]   = ld32(Ahr, wr * 64 + m * 16 + fr, kbb);
            azf[m] = ld32(Azr, wr * 64 + m * 16 + fr, kbb);
        }
#pragma unroll
        for (int n = 0; n < 4; ++n) {
            bh4[n] = ld32(Bhr, wc * 64 + n * 16 + fr, kbb);
            bz4[n] = ld32(Bzr, wc * 64 + n * 16 + fr, kbb);
        }
#pragma unroll
        for (int m = 0; m < 4; ++m)
#pragma unroll
            for (int n = 0; n < 4; ++n) {
                acc_h[m][n] = __builtin_amdgcn_mfma_f32_16x16x32_bf16(a[m], bh4[n], acc_h[m][n], 0, 0, 0);
                acc_z[m][n] = __builtin_amdgcn_mfma_f32_16x16x32_bf16(azf[m], bz4[n], acc_z[m][n], 0, 0, 0);
            }
        __syncthreads();
    }

    float* tf = (float*)lds;
    scatter_acc(tf, acc_z, wr, wc, l);
    __syncthreads();
    u16x8 zreg[8];
#pragma unroll
    for (int i = 0; i < 8; ++i) {
        int chunk = i * 256 + tid;
        int row = chunk >> 4;
        int c8 = (chunk & 15) << 3;
        f32x8 vz = *(const f32x8*)&tf[row * 128 + c8];
        f32x8 ubv = *(const f32x8*)&ub[n0 + c8];
#pragma unroll
        for (int j = 0; j < 8; ++j) {
            float s = 1.f / (1.f + __expf(-(vz[j] + ubv[j])));
            zreg[i][j] = f2bf(s);
        }
    }
    __syncthreads();
    scatter_acc(tf, acc_h, wr, wc, l);
    __syncthreads();
#pragma unroll
    for (int i = 0; i < 8; ++i) {
        int chunk = i * 256 + tid;
        int row = chunk >> 4;
        int c8 = (chunk & 15) << 3;
        int gcol = n0 + c8;
        size_t gbase = (size_t)(m0 + row) * 512 + gcol;
        f32x8 vh = *(const f32x8*)&tf[row * 128 + c8];
        f32x8 hbv = *(const f32x8*)&hb[gcol];
        u16x8 h8 = *(const u16x8*)&Hb[gbase];
        f32x8 o;
#pragma unroll
        for (int j = 0; j < 8; ++j) {
            float t = fast_tanh(vh[j] + hbv[j]);
            float h0 = bf2f(h8[j]);
            float z = bf2f(zreg[i][j]);
            o[j] = h0 + z * (t - h0);
        }
        *(f32x8*)&out[gbase] = o;
    }
}

extern "C" void kernel_launch(void* const* d_in, const int* in_sizes, int n_in,
                              void* d_out, int out_size, void* d_ws, size_t ws_size,
                              hipStream_t stream) {
    const float* x  = (const float*)d_in[0];
    const float* h  = (const float*)d_in[1];
    const float* wz = (const float*)d_in[2];
    const float* wr = (const float*)d_in[3];
    const float* wh = (const float*)d_in[4];
    const float* ub = (const float*)d_in[5];
    const float* rb = (const float*)d_in[6];
    const float* hb = (const float*)d_in[7];
    float* out = (float*)d_out;

    const int B = 16384;
    char* ws = (char*)d_ws;
    size_t off = 0;
    u16* Xb  = (u16*)(ws + off); off += (size_t)B * 512 * 2;      // 16 MB
    u16* Hb  = (u16*)(ws + off); off += (size_t)B * 512 * 2;      // 16 MB
    u16* Wzt = (u16*)(ws + off); off += (size_t)512 * 1024 * 2;   // 1 MB
    u16* Wrt = (u16*)(ws + off); off += (size_t)512 * 1024 * 2;   // 1 MB
    u16* Wht = (u16*)(ws + off); off += (size_t)512 * 1024 * 2;   // 1 MB
    u16* rgh = (u16*)(ws + off); off += (size_t)B * 512 * 2;      // 16 MB

    prep_k<<<2048 + 1536, 256, 0, stream>>>(x, h, wz, wr, wh, Xb, Hb, Wzt, Wrt, Wht);

    gr_k<<<512, 256, 0, stream>>>(Xb, Hb, Wrt, rb, rgh);
    ghz_k<<<512, 256, 0, stream>>>(Xb, Hb, rgh, Wht, Wzt, ub, hb, out);
}

// Round 22
// 95.433 us; speedup vs baseline: 1.0229x; 1.0229x over previous
//
#include <hip/hip_runtime.h>
#include <hip/hip_bf16.h>
#include <math.h>

typedef __attribute__((ext_vector_type(4))) float f32x4;
typedef __attribute__((ext_vector_type(8))) float f32x8;
typedef __bf16 bf16x8 __attribute__((ext_vector_type(8)));
typedef unsigned short u16;
typedef u16 u16x8 __attribute__((ext_vector_type(8)));
typedef void __attribute__((address_space(1))) * as1p;
typedef void __attribute__((address_space(3))) * as3p;

__device__ __forceinline__ unsigned short f2bf(float f) {
    union { float f; unsigned int u; } v; v.f = f;
    unsigned int u = v.u;
    u += 0x7fffu + ((u >> 16) & 1u);   // RNE
    return (unsigned short)(u >> 16);
}

__device__ __forceinline__ float bf2f(unsigned short b) {
    union { unsigned int u; float f; } v;
    v.u = ((unsigned int)b) << 16;
    return v.f;
}

__device__ __forceinline__ float fast_tanh(float v) {
    float vc = fminf(fmaxf(v, -15.f), 15.f);
    float e = __expf(2.f * vc);
    return (e - 1.f) / (e + 1.f);
}

// ---------- fused prepass: cvt x,h -> bf16 AND 3 weight transposes ----------
__global__ void prep_k(const float* __restrict__ x, const float* __restrict__ h,
                       const float* __restrict__ wz, const float* __restrict__ wrr,
                       const float* __restrict__ wh,
                       u16* __restrict__ xb, u16* __restrict__ hb,
                       u16* __restrict__ wzt, u16* __restrict__ wrt, u16* __restrict__ wht) {
    __shared__ float t[32][33];
    int bid = blockIdx.x;
    int tid = threadIdx.x;
    if (bid < 2048) {
        const int n4 = 16384 * 512 / 4;
        int i = bid * 256 + tid;
        const int stride = 2048 * 256;
        const float4* x4 = (const float4*)x;
        const float4* h4 = (const float4*)h;
        ushort4* xb4 = (ushort4*)xb;
        ushort4* hb4 = (ushort4*)hb;
        for (; i < n4; i += stride) {
            float4 v = x4[i];
            xb4[i] = make_ushort4(f2bf(v.x), f2bf(v.y), f2bf(v.z), f2bf(v.w));
            float4 w = h4[i];
            hb4[i] = make_ushort4(f2bf(w.x), f2bf(w.y), f2bf(w.z), f2bf(w.w));
        }
    } else {
        int b = bid - 2048;
        int z = b >> 9;
        int rem = b & 511;
        const float* src = (z == 0) ? wz : (z == 1) ? wrr : wh;
        u16* dst = (z == 0) ? wzt : (z == 1) ? wrt : wht;
        int n0 = (rem & 15) * 32;
        int k0 = (rem >> 4) * 32;
        int tx = tid & 31, ty = tid >> 5;
#pragma unroll
        for (int i = 0; i < 4; ++i)
            t[ty + i * 8][tx] = src[(size_t)(k0 + ty + i * 8) * 512 + n0 + tx];
        __syncthreads();
#pragma unroll
        for (int i = 0; i < 4; ++i)
            dst[(size_t)(n0 + ty + i * 8) * 1024 + k0 + tx] = f2bf(t[tx][ty + i * 8]);
    }
}

// ================= BK=64 machinery (128B rows, row&7 swizzle — conflicts=0) =================
__device__ __forceinline__ void stage_sw(const u16* g, int gstride, u16* lds, int tid) {
#pragma unroll
    for (int i = 0; i < 4; ++i) {
        int ob = i * 4096 + ((tid >> 6) << 10);
        int o = ob + ((tid & 63) << 4);
        int row = o >> 7;
        int cb = (o & 127) ^ ((row & 7) << 4);
        const u16* gp = g + (size_t)row * gstride + (cb >> 1);
        __builtin_amdgcn_global_load_lds((as1p)(void*)gp, (as3p)(void*)(lds + (ob >> 1)), 16, 0, 0);
    }
}

__device__ __forceinline__ bf16x8 ld_frag(const u16* region, int r, int kb) {
    int byte = (r << 7) + (kb ^ ((r & 7) << 4));
    return *(const bf16x8*)((const char*)region + byte);
}

__device__ __forceinline__ void compute_tile(const u16* LA, const u16* LB,
                                             int wr, int wc, int l, f32x4 (&acc)[4][4]) {
    int fr = l & 15;
    int kbb = (l >> 4) << 4;
#pragma unroll
    for (int q = 0; q < 2; ++q) {
        bf16x8 a[4], b[4];
#pragma unroll
        for (int m = 0; m < 4; ++m)
            a[m] = ld_frag(LA, wr * 64 + m * 16 + fr, q * 64 + kbb);
#pragma unroll
        for (int n = 0; n < 4; ++n)
            b[n] = ld_frag(LB, wc * 64 + n * 16 + fr, q * 64 + kbb);
#pragma unroll
        for (int m = 0; m < 4; ++m)
#pragma unroll
            for (int n = 0; n < 4; ++n)
                acc[m][n] = __builtin_amdgcn_mfma_f32_16x16x32_bf16(a[m], b[n], acc[m][n], 0, 0, 0);
    }
}

template<typename AF, typename BF>
__device__ __forceinline__ void kloop(AF ga, BF gb, u16* lds, int tid,
                                      int wr, int wc, int l, f32x4 (&acc)[4][4]) {
    stage_sw(ga(0), 512, lds, tid);
    stage_sw(gb(0), 1024, lds + 8192, tid);
    __syncthreads();
#pragma unroll
    for (int i = 0; i < 15; ++i) {
        u16* nxt = lds + ((i + 1) & 1) * 16384;
        const u16* cur = lds + (i & 1) * 16384;
        stage_sw(ga(i + 1), 512, nxt, tid);
        stage_sw(gb(i + 1), 1024, nxt + 8192, tid);
        compute_tile(cur, cur + 8192, wr, wc, l, acc);
        __syncthreads();
    }
    compute_tile(lds + 16384, lds + 16384 + 8192, wr, wc, l, acc);
}

// ---------- scatter acc into f32 [128][128] LDS tile ----------
__device__ __forceinline__ void scatter_acc(float* tf, const f32x4 (&acc)[4][4],
                                            int wr, int wc, int l) {
    int colb = wc * 64;
    int rowb = wr * 64 + ((l >> 4) << 2);
#pragma unroll
    for (int n = 0; n < 4; ++n) {
        int col = colb + n * 16 + (l & 15);
#pragma unroll
        for (int m = 0; m < 4; ++m) {
            int row0 = rowb + m * 16;
#pragma unroll
            for (int r = 0; r < 4; ++r)
                tf[(row0 + r) * 128 + col] = acc[m][n][r];
        }
    }
}

// ================= gr: [X|H] @ Wr^T -> rgh = bf16(sigmoid * h) =================
__global__ __launch_bounds__(256) void gr_k(
    const u16* __restrict__ Xb, const u16* __restrict__ Hb, const u16* __restrict__ Wt,
    const float* __restrict__ rb_, u16* __restrict__ rgh) {
    __shared__ u16 lds[2 * 16384];
    int tid = threadIdx.x;
    int l = tid & 63, w = tid >> 6;
    int wr = w >> 1, wc = w & 1;
    int swz = (blockIdx.x & 7) * 64 + (blockIdx.x >> 3);
    int mb = swz >> 2, nb = swz & 3;
    int m0 = mb * 128, n0 = nb * 128;
    f32x4 acc[4][4];
#pragma unroll
    for (int m = 0; m < 4; ++m)
#pragma unroll
        for (int n = 0; n < 4; ++n) acc[m][n] = (f32x4){0.f, 0.f, 0.f, 0.f};

    auto ga = [&](int t) -> const u16* {
        return (t < 8) ? (Xb + (size_t)m0 * 512 + t * 64)
                       : (Hb + (size_t)m0 * 512 + (t - 8) * 64);
    };
    auto gb = [&](int t) -> const u16* { return Wt + (size_t)n0 * 1024 + t * 64; };
    kloop(ga, gb, lds, tid, wr, wc, l, acc);

    __syncthreads();
    float* tf = (float*)lds;
    scatter_acc(tf, acc, wr, wc, l);
    __syncthreads();
#pragma unroll
    for (int i = 0; i < 8; ++i) {
        int chunk = i * 256 + tid;
        int row = chunk >> 4;
        int c8 = (chunk & 15) << 3;
        const float* src = &tf[row * 128 + c8];
        int gcol = n0 + c8;
        size_t gbase = (size_t)(m0 + row) * 512 + gcol;
        u16x8 h8 = *(const u16x8*)&Hb[gbase];
        u16x8 o;
#pragma unroll
        for (int j = 0; j < 8; ++j) {
            float v = src[j] + rb_[gcol + j];
            float s = 1.f / (1.f + __expf(-v));
            o[j] = f2bf(s * bf2f(h8[j]));
        }
        *(u16x8*)&rgh[gbase] = o;
    }
}

// ================= BK=32 machinery =================
__device__ __forceinline__ void stage32(const u16* g, int gstride, u16* region, int tid) {
#pragma unroll
    for (int i = 0; i < 2; ++i) {
        int ob = i * 4096 + ((tid >> 6) << 10);
        int o = ob + ((tid & 63) << 4);
        int row = o >> 6;
        int cb = (o & 63) ^ ((row & 3) << 4);
        const u16* gp = g + (size_t)row * gstride + (cb >> 1);
        __builtin_amdgcn_global_load_lds((as1p)(void*)gp, (as3p)(void*)(region + (ob >> 1)), 16, 0, 0);
    }
}

__device__ __forceinline__ bf16x8 ld32(const u16* region, int r, int kb) {
    int byte = (r << 6) + (kb ^ ((r & 3) << 4));
    return *(const bf16x8*)((const char*)region + byte);
}

// ================= ghz: fused z-gate + hidden GEMM -> out fp32 =================
__global__ __launch_bounds__(256, 2) void ghz_k(
    const u16* __restrict__ Xb, const u16* __restrict__ Hb, const u16* __restrict__ rgh,
    const u16* __restrict__ Wht, const u16* __restrict__ Wzt,
    const float* __restrict__ ub, const float* __restrict__ hb,
    float* __restrict__ out) {
    __shared__ u16 lds[2 * 16384];
    int tid = threadIdx.x;
    int l = tid & 63, w = tid >> 6;
    int wr = w >> 1, wc = w & 1;
    int swz = (blockIdx.x & 7) * 64 + (blockIdx.x >> 3);
    int mb = swz >> 2, nb = swz & 3;
    int m0 = mb * 128, n0 = nb * 128;

    f32x4 acc_h[4][4], acc_z[4][4];
#pragma unroll
    for (int m = 0; m < 4; ++m)
#pragma unroll
        for (int n = 0; n < 4; ++n) {
            acc_h[m][n] = (f32x4){0.f, 0.f, 0.f, 0.f};
            acc_z[m][n] = (f32x4){0.f, 0.f, 0.f, 0.f};
        }

    auto ah = [&](int t) -> const u16* {
        return (t < 16) ? (Xb + (size_t)m0 * 512 + t * 32)
                        : (rgh + (size_t)m0 * 512 + (t - 16) * 32);
    };
    auto az = [&](int t) -> const u16* {
        return Hb + (size_t)m0 * 512 + (t - 16) * 32;
    };
    auto bhp = [&](int t) -> const u16* { return Wht + (size_t)n0 * 1024 + t * 32; };
    auto bzp = [&](int t) -> const u16* { return Wzt + (size_t)n0 * 1024 + t * 32; };

    const int fr = l & 15;
    const int kbb = (l >> 4) << 4;

    stage32(ah(0), 512, lds, tid);
    stage32(bhp(0), 1024, lds + 8192, tid);
    stage32(bzp(0), 1024, lds + 12288, tid);
    __syncthreads();

#pragma unroll
    for (int i = 0; i < 32; ++i) {
        const u16* cur = lds + (i & 1) * 16384;
        if (i < 31) {
            u16* nxt = lds + ((i + 1) & 1) * 16384;
            stage32(ah(i + 1), 512, nxt, tid);
            if (i + 1 >= 16) stage32(az(i + 1), 512, nxt + 4096, tid);
            stage32(bhp(i + 1), 1024, nxt + 8192, tid);
            stage32(bzp(i + 1), 1024, nxt + 12288, tid);
        }
        const u16* Ahr = cur;
        const u16* Azr = (i < 16) ? cur : (cur + 4096);
        const u16* Bhr = cur + 8192;
        const u16* Bzr = cur + 12288;
        bf16x8 a[4], azf[4], bh4[4], bz4[4];
#pragma unroll
        for (int m = 0; m < 4; ++m) {
            a[m]   = ld32(Ahr, wr * 64 + m * 16 + fr, kbb);
            azf[m] = ld32(Azr, wr * 64 + m * 16 + fr, kbb);
        }
#pragma unroll
        for (int n = 0; n < 4; ++n) {
            bh4[n] = ld32(Bhr, wc * 64 + n * 16 + fr, kbb);
            bz4[n] = ld32(Bzr, wc * 64 + n * 16 + fr, kbb);
        }
#pragma unroll
        for (int m = 0; m < 4; ++m)
#pragma unroll
            for (int n = 0; n < 4; ++n) {
                acc_h[m][n] = __builtin_amdgcn_mfma_f32_16x16x32_bf16(a[m], bh4[n], acc_h[m][n], 0, 0, 0);
                acc_z[m][n] = __builtin_amdgcn_mfma_f32_16x16x32_bf16(azf[m], bz4[n], acc_z[m][n], 0, 0, 0);
            }
        __syncthreads();
    }

    float* tf = (float*)lds;
    scatter_acc(tf, acc_z, wr, wc, l);
    __syncthreads();
    u16x8 zreg[8];
#pragma unroll
    for (int i = 0; i < 8; ++i) {
        int chunk = i * 256 + tid;
        int row = chunk >> 4;
        int c8 = (chunk & 15) << 3;
        f32x8 vz = *(const f32x8*)&tf[row * 128 + c8];
        f32x8 ubv = *(const f32x8*)&ub[n0 + c8];
#pragma unroll
        for (int j = 0; j < 8; ++j) {
            float s = 1.f / (1.f + __expf(-(vz[j] + ubv[j])));
            zreg[i][j] = f2bf(s);
        }
    }
    __syncthreads();
    scatter_acc(tf, acc_h, wr, wc, l);
    __syncthreads();
#pragma unroll
    for (int i = 0; i < 8; ++i) {
        int chunk = i * 256 + tid;
        int row = chunk >> 4;
        int c8 = (chunk & 15) << 3;
        int gcol = n0 + c8;
        size_t gbase = (size_t)(m0 + row) * 512 + gcol;
        f32x8 vh = *(const f32x8*)&tf[row * 128 + c8];
        f32x8 hbv = *(const f32x8*)&hb[gcol];
        u16x8 h8 = *(const u16x8*)&Hb[gbase];
        f32x8 o;
#pragma unroll
        for (int j = 0; j < 8; ++j) {
            float t = fast_tanh(vh[j] + hbv[j]);
            float h0 = bf2f(h8[j]);
            float z = bf2f(zreg[i][j]);
            o[j] = h0 + z * (t - h0);
        }
        *(f32x8*)&out[gbase] = o;
    }
}

extern "C" void kernel_launch(void* const* d_in, const int* in_sizes, int n_in,
                              void* d_out, int out_size, void* d_ws, size_t ws_size,
                              hipStream_t stream) {
    const float* x  = (const float*)d_in[0];
    const float* h  = (const float*)d_in[1];
    const float* wz = (const float*)d_in[2];
    const float* wr = (const float*)d_in[3];
    const float* wh = (const float*)d_in[4];
    const float* ub = (const float*)d_in[5];
    const float* rb = (const float*)d_in[6];
    const float* hb = (const float*)d_in[7];
    float* out = (float*)d_out;

    const int B = 16384;
    char* ws = (char*)d_ws;
    size_t off = 0;
    u16* Xb  = (u16*)(ws + off); off += (size_t)B * 512 * 2;      // 16 MB
    u16* Hb  = (u16*)(ws + off); off += (size_t)B * 512 * 2;      // 16 MB
    u16* Wzt = (u16*)(ws + off); off += (size_t)512 * 1024 * 2;   // 1 MB
    u16* Wrt = (u16*)(ws + off); off += (size_t)512 * 1024 * 2;   // 1 MB
    u16* Wht = (u16*)(ws + off); off += (size_t)512 * 1024 * 2;   // 1 MB
    u16* rgh = (u16*)(ws + off); off += (size_t)B * 512 * 2;      // 16 MB

    prep_k<<<2048 + 1536, 256, 0, stream>>>(x, h, wz, wr, wh, Xb, Hb, Wzt, Wrt, Wht);

    gr_k<<<512, 256, 0, stream>>>(Xb, Hb, Wrt, rb, rgh);
    ghz_k<<<512, 256, 0, stream>>>(Xb, Hb, rgh, Wht, Wzt, ub, hb, out);
}